// Round 4
// baseline (2976.516 us; speedup 1.0000x reference)
//
#include <hip/hip_runtime.h>
#include <hip/hip_bf16.h>

#pragma clang fp contract(off)

#define TT 512
#define CC 256
#define TPAD 257
#define INFV 1e9f

__device__ __forceinline__ unsigned long long packkey(float v, unsigned c) {
  return ((unsigned long long)__float_as_uint(v) << 32) | (unsigned long long)c;
}

// ---------------- Phase 1: distance matrix + initial row-min keys ----------------
// (unchanged from round 2 — measured 529 us, correct; isolating agglom changes)
__device__ void load_norm_tile(const float* __restrict__ xb, int rowBase,
                               float (*S)[TPAD], double* part, int tid) {
  for (int idx = tid; idx < 64 * CC; idx += 256) {
    int r = idx >> 8;
    int c = idx & (CC - 1);
    S[r][c] = xb[(size_t)(rowBase + r) * CC + c];
  }
  __syncthreads();
  {
    int r = tid >> 2, p = tid & 3;
    double s = 0.0;
    int c0 = p * 64;
    for (int c = 0; c < 64; ++c) {
      double v = (double)S[r][c0 + c];
      s = fma(v, v, s);
    }
    part[tid] = s;
  }
  __syncthreads();
  if ((tid & 3) == 0) {
    double tot = part[tid] + part[tid + 1] + part[tid + 2] + part[tid + 3];
    part[tid] = sqrt(tot) + 1e-8;  // norm + EPS, in f64
  }
  __syncthreads();
  for (int idx = tid; idx < 64 * CC; idx += 256) {
    int r = idx >> 8;
    int c = idx & (CC - 1);
    S[r][c] = (float)((double)S[r][c] / part[r << 2]);
  }
  __syncthreads();
}

__global__ __launch_bounds__(256) void build_dist_kernel(
    const float* __restrict__ x, float* __restrict__ dall,
    unsigned long long* __restrict__ rkall) {
  __shared__ float A[64][TPAD];
  __shared__ float Bs[64][TPAD];
  __shared__ double part[256];
  __shared__ unsigned long long rkl[64];

  int ta = blockIdx.x;   // row tile 0..7
  int b  = blockIdx.y;   // batch
  const float* xb = x + (size_t)b * TT * CC;
  float* d = dall + (size_t)b * TT * TT;
  int tid = threadIdx.x;
  if (tid < 64) rkl[tid] = ~0ull;
  load_norm_tile(xb, ta * 64, A, part, tid);

  int ty = tid & 15;   // col group (contiguous cols -> coalesced float4 stores)
  int tx = tid >> 4;   // row group
  for (int tb = 0; tb < 8; ++tb) {
    __syncthreads();   // previous Bs consumers done
    load_norm_tile(xb, tb * 64, Bs, part, tid);
    double acc[4][4];
#pragma unroll
    for (int ia = 0; ia < 4; ++ia)
#pragma unroll
      for (int ib = 0; ib < 4; ++ib) acc[ia][ib] = 0.0;
    for (int k = 0; k < CC; ++k) {
      double av[4], bv[4];
#pragma unroll
      for (int ia = 0; ia < 4; ++ia) av[ia] = (double)A[4 * tx + ia][k];
#pragma unroll
      for (int ib = 0; ib < 4; ++ib) bv[ib] = (double)Bs[4 * ty + ib][k];
#pragma unroll
      for (int ia = 0; ia < 4; ++ia)
#pragma unroll
        for (int ib = 0; ib < 4; ++ib)
          acc[ia][ib] = fma(av[ia], bv[ib], acc[ia][ib]);
    }
#pragma unroll
    for (int ia = 0; ia < 4; ++ia) {
      int gr = ta * 64 + 4 * tx + ia;
      int gcBase = tb * 64 + 4 * ty;
      float vt[4];
      unsigned long long key = ~0ull;
#pragma unroll
      for (int ib = 0; ib < 4; ++ib) {
        int gc = gcBase + ib;
        float v = (gr == gc) ? INFV : (float)(1.0 - acc[ia][ib]);
        vt[ib] = v;
        unsigned long long kk = packkey(v, (unsigned)gc);
        if (kk < key) key = kk;
      }
      *(float4*)(&d[(size_t)gr * TT + gcBase]) =
          make_float4(vt[0], vt[1], vt[2], vt[3]);
#pragma unroll
      for (int off = 1; off < 16; off <<= 1) {
        unsigned long long o = __shfl_xor(key, off, 64);
        if (o < key) key = o;
      }
      if (ty == 0) atomicMin(&rkl[4 * tx + ia], key);
    }
  }
  __syncthreads();
  if (tid < 64) rkall[(size_t)b * TT + ta * 64 + tid] = rkl[tid];
}

// ---------------- Phase 2: sequential agglomerative merging, one wave/batch ----------------
// Restructured vs round 2:
//  - no col-j INF stores (dead cols masked via aliveM bitmask in LDS); the
//    UPDATE path must therefore also mask dead columns when folding ikey and
//    writing row i back (stale finite values in memory would corrupt the min)
//  - ONE fence/iter, placed after argmin (LDS-only) and before row loads, so
//    the previous iteration's scattered col-i stores drain in the shadow of
//    rescans + argmin
//  - rescans patch col i from nvs[] (LDS copy of the new row) instead of
//    waiting on this iteration's stores
//  - rescan rows processed 2 at a time with interleaved reductions
__global__ __launch_bounds__(64) void agglom_kernel(
    const int* __restrict__ ncp, float* __restrict__ dall,
    const unsigned long long* __restrict__ rkall, int* __restrict__ outp) {
  __shared__ unsigned long long rk[TT];   // (valbits<<32)|first-min-col per row
  __shared__ float sizes[TT];
  __shared__ float4 nvs4[TT / 4];         // this-iter new row i values (16B aligned)
  __shared__ int assign[TT];
  __shared__ int rankArr[TT];
  __shared__ int rlist[TT];               // compacted rescan list
  __shared__ unsigned aliveM[TT / 32];    // bit c = col c alive
  float* nvs = (float*)nvs4;

  int b = blockIdx.x;
  int lane = threadIdx.x;
  float* d = dall + (size_t)b * TT * TT;
#pragma unroll
  for (int u = 0; u < 8; ++u) {
    int r = u * 64 + lane;
    rk[r] = rkall[(size_t)b * TT + r];
    sizes[r] = 1.0f;
    assign[r] = r;
  }
  if (lane < TT / 32) aliveM[lane] = 0xFFFFFFFFu;
  int K = ncp[0];
  if (K > TT) K = TT;
  if (K < 1) K = 1;
  int nm = TT - K;

  for (int iter = 0; iter < nm; ++iter) {
    // ---- global argmin over cached row keys: (val, row) lexicographic (LDS only)
    unsigned long long best = ~0ull;
#pragma unroll
    for (int u = 0; u < 8; ++u) {
      int r = u * 64 + lane;
      unsigned long long key =
          (rk[r] & 0xFFFFFFFF00000000ull) | (unsigned long long)(unsigned)r;
      if (key < best) best = key;
    }
#pragma unroll
    for (int off = 32; off >= 1; off >>= 1) {
      unsigned long long o = __shfl_xor(best, off, 64);
      if (o < best) best = o;
    }
    int i = (int)(best & 0xFFFFFFFFull);   // smaller flat index => row wins tie
    int j = (int)(rk[i] & 0xFFFFFFFFull);  // its first-min column
    float ni = sizes[i], nj = sizes[j];
    float denom = ni + nj;

    // ---- fence: previous iteration's scattered stores must be visible to the
    // row loads below. By now they have had the whole rescan+argmin window to
    // drain, so this wait is mostly free.
    __threadfence_block();

    // ---- load rows i and j (contiguous float4 per lane)
    const float4* pi = (const float4*)(d + (size_t)i * TT);
    const float4* pj = (const float4*)(d + (size_t)j * TT);
    float4 di0 = pi[lane * 2], di1 = pi[lane * 2 + 1];
    float4 dj0 = pj[lane * 2], dj1 = pj[lane * 2 + 1];

    // ---- newrow = (ni*d[i] + nj*d[j]) / (ni+nj); store row i + scattered col i.
    // Dead columns hold stale finite values in memory (no kill stores) -> mask
    // them to INFV here so ikey and the written-back row stay correct.
    int cbase = lane * 8;
    unsigned aw = aliveM[lane >> 2];       // j's bit still set; c==j handled below
    float w[8];
    unsigned long long ikey = ~0ull;
#pragma unroll
    for (int t = 0; t < 8; ++t) {
      int c = cbase + t;
      bool alive = (aw >> (((lane & 3) << 3) + t)) & 1;
      float a  = t < 4 ? (&di0.x)[t] : (&di1.x)[t - 4];
      float bb = t < 4 ? (&dj0.x)[t] : (&dj1.x)[t - 4];
      float v = (ni * a + nj * bb) / denom;  // contract(off): mul,mul,add,div
      float ww = (c == i || c == j || !alive) ? INFV : v;
      w[t] = ww;
      d[(size_t)c * TT + i] = ww;            // scattered col-i store (not waited on)
      unsigned long long kk = packkey(ww, (unsigned)c);
      if (kk < ikey) ikey = kk;
    }
    float4 w0 = make_float4(w[0], w[1], w[2], w[3]);
    float4 w1 = make_float4(w[4], w[5], w[6], w[7]);
    ((float4*)(d + (size_t)i * TT))[lane * 2] = w0;      // coalesced row-i store
    ((float4*)(d + (size_t)i * TT))[lane * 2 + 1] = w1;
    nvs4[lane * 2] = w0;                                 // LDS copy for patching
    nvs4[lane * 2 + 1] = w1;
#pragma unroll
    for (int off = 32; off >= 1; off >>= 1) {
      unsigned long long o = __shfl_xor(ikey, off, 64);
      if (o < ikey) ikey = o;
    }

    // ---- lazy row-min maintenance + assign update (per-row ownership)
    unsigned fl = 0;
#pragma unroll
    for (int u = 0; u < 8; ++u) {
      int r = u * 64 + lane;
      if (r != i && r != j && sizes[r] > 0.0f) {
        unsigned long long cur = rk[r];
        unsigned c = (unsigned)(cur & 0xFFFFFFFFull);
        if (c == (unsigned)i || c == (unsigned)j) {
          fl |= (1u << u);                   // cached min invalidated -> rescan
        } else {
          unsigned long long nk = packkey(nvs[r], (unsigned)i);
          if (nk < cur) rk[r] = nk;          // equal-value, smaller-col handled
        }
      }
      if (assign[r] == j) assign[r] = i;
    }
    if (lane == 0) {
      sizes[i] = denom;
      sizes[j] = 0.0f;
      rk[i] = ikey;
      rk[j] = packkey(INFV, 0xFFFFFFFFu);
      aliveM[j >> 5] &= ~(1u << (j & 31));   // col j dies (no INF stores)
    }

    // ---- compact list of rows needing rescan
    int cnt = 0;
#pragma unroll
    for (int u = 0; u < 8; ++u) {
      unsigned long long mask = __ballot((fl >> u) & 1);
      if ((fl >> u) & 1) {
        int pos = cnt + __popcll(mask & ((1ull << lane) - 1ull));
        rlist[pos] = u * 64 + lane;
      }
      cnt += __popcll(mask);
    }

    // ---- rescan invalidated rows, 2 at a time (patched: no dependence on
    // this iteration's global stores)
    for (int k2 = 0; k2 < cnt; k2 += 2) {
      int r0 = rlist[k2];
      int r1 = (k2 + 1 < cnt) ? rlist[k2 + 1] : r0;
      const float4* p0 = (const float4*)(d + (size_t)r0 * TT);
      const float4* p1 = (const float4*)(d + (size_t)r1 * TT);
      float4 x0 = p0[lane * 2], x1 = p0[lane * 2 + 1];
      float4 y0 = p1[lane * 2], y1 = p1[lane * 2 + 1];
      float pv0 = nvs[r0], pv1 = nvs[r1];
      unsigned awr = aliveM[lane >> 2];     // j's bit cleared by now
      unsigned long long k0 = ~0ull, k1 = ~0ull;
#pragma unroll
      for (int t = 0; t < 8; ++t) {
        int c = cbase + t;
        bool alive = (awr >> (((lane & 3) << 3) + t)) & 1;
        float e0 = t < 4 ? (&x0.x)[t] : (&x1.x)[t - 4];
        float e1 = t < 4 ? (&y0.x)[t] : (&y1.x)[t - 4];
        e0 = (c == i) ? pv0 : (alive ? e0 : INFV);
        e1 = (c == i) ? pv1 : (alive ? e1 : INFV);
        unsigned long long kk0 = packkey(e0, (unsigned)c); if (kk0 < k0) k0 = kk0;
        unsigned long long kk1 = packkey(e1, (unsigned)c); if (kk1 < k1) k1 = kk1;
      }
#pragma unroll
      for (int off = 32; off >= 1; off >>= 1) {
        unsigned long long o0 = __shfl_xor(k0, off, 64); if (o0 < k0) k0 = o0;
        unsigned long long o1 = __shfl_xor(k1, off, 64); if (o1 < k1) k1 = o1;
      }
      if (lane == 0) { rk[r0] = k0; rk[r1] = k1; }
    }
  }

  // ---- canonical relabel: assign[t] == min original index of t's cluster
  int isf[8];
  int cntf = 0;
#pragma unroll
  for (int t = 0; t < 8; ++t) {
    int r = lane * 8 + t;
    isf[t] = (assign[r] == r) ? 1 : 0;
    cntf += isf[t];
  }
  int incl = cntf;
#pragma unroll
  for (int off = 1; off < 64; off <<= 1) {
    int o = __shfl_up(incl, (unsigned)off, 64);
    if (lane >= off) incl += o;
  }
  int base = incl - cntf;
#pragma unroll
  for (int t = 0; t < 8; ++t) {
    int r = lane * 8 + t;
    if (isf[t]) rankArr[r] = base++;
  }
#pragma unroll
  for (int u = 0; u < 8; ++u) {
    int r = u * 64 + lane;
    outp[(size_t)b * TT + r] = rankArr[assign[r]];
  }
}

extern "C" void kernel_launch(void* const* d_in, const int* in_sizes, int n_in,
                              void* d_out, int out_size, void* d_ws, size_t ws_size,
                              hipStream_t stream) {
  const float* x = (const float*)d_in[0];
  const int* ncp = (const int*)d_in[1];
  int B = in_sizes[0] / (TT * CC);
  float* dall = (float*)d_ws;                                   // B * 512*512 f32 (64 MiB)
  unsigned long long* rkall =
      (unsigned long long*)((char*)d_ws + (size_t)B * TT * TT * sizeof(float));
  int* outp = (int*)d_out;

  dim3 g1(TT / 64, B);
  build_dist_kernel<<<g1, 256, 0, stream>>>(x, dall, rkall);
  agglom_kernel<<<B, 64, 0, stream>>>(ncp, dall, rkall, outp);
}

// Round 7
// 1884.367 us; speedup vs baseline: 1.5796x; 1.5796x over previous
//
#include <hip/hip_runtime.h>
#include <hip/hip_bf16.h>

#pragma clang fp contract(off)

#define TT 512
#define CC 256
#define TPAD 257
#define INFV 1e9f

__device__ __forceinline__ unsigned long long packkey(float v, unsigned c) {
  return ((unsigned long long)__float_as_uint(v) << 32) | (unsigned long long)c;
}

__device__ __forceinline__ unsigned long long wave_min_u64(unsigned long long k) {
#pragma unroll
  for (int off = 32; off >= 1; off >>= 1) {
    unsigned long long o = __shfl_xor(k, off, 64);
    if (o < k) k = o;
  }
  return k;
}

// ---------------- Phase 1: distance matrix + initial row-min keys ----------------
// (unchanged — measured 529 us, absmax 0.0; agglom changes isolated)
__device__ void load_norm_tile(const float* __restrict__ xb, int rowBase,
                               float (*S)[TPAD], double* part, int tid) {
  for (int idx = tid; idx < 64 * CC; idx += 256) {
    int r = idx >> 8;
    int c = idx & (CC - 1);
    S[r][c] = xb[(size_t)(rowBase + r) * CC + c];
  }
  __syncthreads();
  {
    int r = tid >> 2, p = tid & 3;
    double s = 0.0;
    int c0 = p * 64;
    for (int c = 0; c < 64; ++c) {
      double v = (double)S[r][c0 + c];
      s = fma(v, v, s);
    }
    part[tid] = s;
  }
  __syncthreads();
  if ((tid & 3) == 0) {
    double tot = part[tid] + part[tid + 1] + part[tid + 2] + part[tid + 3];
    part[tid] = sqrt(tot) + 1e-8;  // norm + EPS, in f64
  }
  __syncthreads();
  for (int idx = tid; idx < 64 * CC; idx += 256) {
    int r = idx >> 8;
    int c = idx & (CC - 1);
    S[r][c] = (float)((double)S[r][c] / part[r << 2]);
  }
  __syncthreads();
}

__global__ __launch_bounds__(256) void build_dist_kernel(
    const float* __restrict__ x, float* __restrict__ dall,
    unsigned long long* __restrict__ rkall) {
  __shared__ float A[64][TPAD];
  __shared__ float Bs[64][TPAD];
  __shared__ double part[256];
  __shared__ unsigned long long rkl[64];

  int ta = blockIdx.x;   // row tile 0..7
  int b  = blockIdx.y;   // batch
  const float* xb = x + (size_t)b * TT * CC;
  float* d = dall + (size_t)b * TT * TT;
  int tid = threadIdx.x;
  if (tid < 64) rkl[tid] = ~0ull;
  load_norm_tile(xb, ta * 64, A, part, tid);

  int ty = tid & 15;   // col group (contiguous cols -> coalesced float4 stores)
  int tx = tid >> 4;   // row group
  for (int tb = 0; tb < 8; ++tb) {
    __syncthreads();   // previous Bs consumers done
    load_norm_tile(xb, tb * 64, Bs, part, tid);
    double acc[4][4];
#pragma unroll
    for (int ia = 0; ia < 4; ++ia)
#pragma unroll
      for (int ib = 0; ib < 4; ++ib) acc[ia][ib] = 0.0;
    for (int k = 0; k < CC; ++k) {
      double av[4], bv[4];
#pragma unroll
      for (int ia = 0; ia < 4; ++ia) av[ia] = (double)A[4 * tx + ia][k];
#pragma unroll
      for (int ib = 0; ib < 4; ++ib) bv[ib] = (double)Bs[4 * ty + ib][k];
#pragma unroll
      for (int ia = 0; ia < 4; ++ia)
#pragma unroll
        for (int ib = 0; ib < 4; ++ib)
          acc[ia][ib] = fma(av[ia], bv[ib], acc[ia][ib]);
    }
#pragma unroll
    for (int ia = 0; ia < 4; ++ia) {
      int gr = ta * 64 + 4 * tx + ia;
      int gcBase = tb * 64 + 4 * ty;
      float vt[4];
      unsigned long long key = ~0ull;
#pragma unroll
      for (int ib = 0; ib < 4; ++ib) {
        int gc = gcBase + ib;
        float v = (gr == gc) ? INFV : (float)(1.0 - acc[ia][ib]);
        vt[ib] = v;
        unsigned long long kk = packkey(v, (unsigned)gc);
        if (kk < key) key = kk;
      }
      *(float4*)(&d[(size_t)gr * TT + gcBase]) =
          make_float4(vt[0], vt[1], vt[2], vt[3]);
#pragma unroll
      for (int off = 1; off < 16; off <<= 1) {
        unsigned long long o = __shfl_xor(key, off, 64);
        if (o < key) key = o;
      }
      if (ty == 0) atomicMin(&rkl[4 * tx + ia], key);
    }
  }
  __syncthreads();
  if (tid < 64) rkall[(size_t)b * TT + ta * 64 + tid] = rkl[tid];
}

// ---------------- Phase 2: agglomerative merging, 4 waves (256 threads) per batch ----
// Round-2 memory discipline (PASSED, absmax 0.0): col-j kill stores so global
// memory is always the full truth (dead cols/diag = INFV); no masks, no
// patching. Parallelized across 4 waves with __syncthreads phases (each barrier
// drains vmcnt -> stores visible to post-barrier loads):
//   P0 argmin (2 keys/thread, wave reduce, LDS partials)  B1
//   P1 load rows i,j (float2/thread), compute w, nvs, ikey partials; zero nresc  B2
//   P2 stores (row i, col i, col j kills); tid0 finalizes rk/sizes;
//      flag/lazy/assign on 2 own rows; flagged rows -> rlist via LDS atomicAdd  B3
//   P3 rescans: wave w takes rlist[w], [w+4], ... -> PARALLEL rescans, raw reads  B4
// Merge arithmetic / key packing / tie-breaks bitwise-identical to round 2.
__global__ __launch_bounds__(256) void agglom_kernel(
    const int* __restrict__ ncp, float* __restrict__ dall,
    const unsigned long long* __restrict__ rkall, int* __restrict__ outp) {
  __shared__ unsigned long long rk[TT];
  __shared__ float sizes[TT];
  __shared__ float nvs[TT];
  __shared__ int assign[TT];
  __shared__ int rankArr[TT];
  __shared__ int rlist[TT];
  __shared__ unsigned long long pm[4];    // per-wave argmin partials
  __shared__ unsigned long long pmi[4];   // per-wave row-i-min partials
  __shared__ int wsum[4];
  __shared__ int nresc;

  int b = blockIdx.x;
  int tid = threadIdx.x;
  int lane = tid & 63;
  int w = tid >> 6;
  float* d = dall + (size_t)b * TT * TT;
  int rA = tid * 2, rB = tid * 2 + 1;   // this thread's owned rows / cols

  rk[rA] = rkall[(size_t)b * TT + rA];
  rk[rB] = rkall[(size_t)b * TT + rB];
  sizes[rA] = 1.0f; sizes[rB] = 1.0f;
  assign[rA] = rA;  assign[rB] = rB;
  if (tid == 0) nresc = 0;
  int K = ncp[0];
  if (K > TT) K = TT;
  if (K < 1) K = 1;
  int nm = TT - K;
  __syncthreads();

  for (int iter = 0; iter < nm; ++iter) {
    // ---- P0: global argmin over cached row keys, (val,row) lexicographic
    unsigned long long kA =
        (rk[rA] & 0xFFFFFFFF00000000ull) | (unsigned long long)(unsigned)rA;
    unsigned long long kB =
        (rk[rB] & 0xFFFFFFFF00000000ull) | (unsigned long long)(unsigned)rB;
    unsigned long long best = kA < kB ? kA : kB;
    best = wave_min_u64(best);
    if (lane == 0) pm[w] = best;
    __syncthreads();                                   // B1
    best = pm[0];
    if (pm[1] < best) best = pm[1];
    if (pm[2] < best) best = pm[2];
    if (pm[3] < best) best = pm[3];
    int i = (int)(best & 0xFFFFFFFFull);   // smallest flat index => row wins tie
    int j = (int)(rk[i] & 0xFFFFFFFFull);  // its first-min column (j > i)
    float ni = sizes[i], nj = sizes[j];
    float denom = ni + nj;
    if (tid == 0) nresc = 0;               // safe: old value consumed pre-B4

    // ---- P1: load rows i,j (prev-iter stores drained at prior barriers),
    // compute newrow = (ni*d[i] + nj*d[j]) / (ni+nj)  [contract(off)]
    float2 a2 = *(const float2*)(d + (size_t)i * TT + rA);
    float2 b2 = *(const float2*)(d + (size_t)j * TT + rA);
    float v0 = (ni * a2.x + nj * b2.x) / denom;
    float v1 = (ni * a2.y + nj * b2.y) / denom;
    float w0 = (rA == i || rA == j) ? INFV : v0;
    float w1 = (rB == i || rB == j) ? INFV : v1;
    nvs[rA] = w0; nvs[rB] = w1;
    unsigned long long ik = packkey(w0, (unsigned)rA);
    unsigned long long ik2 = packkey(w1, (unsigned)rB);
    if (ik2 < ik) ik = ik2;
    ik = wave_min_u64(ik);
    if (lane == 0) pmi[w] = ik;
    __syncthreads();                                   // B2 (nvs, pmi visible)

    // ---- P2: stores + bookkeeping + flag/lazy
    *(float2*)(d + (size_t)i * TT + rA) = make_float2(w0, w1);  // row i
    d[(size_t)rA * TT + i] = w0;                                // col i scatter
    d[(size_t)rB * TT + i] = w1;
    d[(size_t)rA * TT + j] = INFV;                              // col j kill
    d[(size_t)rB * TT + j] = INFV;
    if (tid == 0) {
      unsigned long long ikey = pmi[0];
      if (pmi[1] < ikey) ikey = pmi[1];
      if (pmi[2] < ikey) ikey = pmi[2];
      if (pmi[3] < ikey) ikey = pmi[3];
      sizes[i] = denom;
      sizes[j] = 0.0f;
      rk[i] = ikey;
      rk[j] = packkey(INFV, 0xFFFFFFFFu);
    }
#pragma unroll
    for (int t = 0; t < 2; ++t) {
      int r = rA + t;
      if (r != i && r != j && sizes[r] > 0.0f) {   // guards exclude tid0's targets
        unsigned long long cur = rk[r];
        unsigned c = (unsigned)(cur & 0xFFFFFFFFull);
        if (c == (unsigned)i || c == (unsigned)j) {
          int p = atomicAdd(&nresc, 1);            // order in rlist irrelevant
          rlist[p] = r;
        } else {
          unsigned long long nk = packkey(nvs[r], (unsigned)i);
          if (nk < cur) rk[r] = nk;                // equal-val smaller-col too
        }
      }
      if (assign[r] == j) assign[r] = i;
    }
    __syncthreads();                               // B3 (stores drained, rlist ready)

    // ---- P3: rescans, one row per wave in parallel; raw reads (memory = truth)
    int nr = nresc;
    for (int q = w; q < nr; q += 4) {
      int rr = rlist[q];
      const float4* p = (const float4*)(d + (size_t)rr * TT);
      float4 x0 = p[lane * 2];
      float4 x1 = p[lane * 2 + 1];
      int cb = lane * 8;
      unsigned long long key = packkey(x0.x, cb);
      unsigned long long kk;
      kk = packkey(x0.y, cb + 1); if (kk < key) key = kk;
      kk = packkey(x0.z, cb + 2); if (kk < key) key = kk;
      kk = packkey(x0.w, cb + 3); if (kk < key) key = kk;
      kk = packkey(x1.x, cb + 4); if (kk < key) key = kk;
      kk = packkey(x1.y, cb + 5); if (kk < key) key = kk;
      kk = packkey(x1.z, cb + 6); if (kk < key) key = kk;
      kk = packkey(x1.w, cb + 7); if (kk < key) key = kk;
      key = wave_min_u64(key);
      if (lane == 0) rk[rr] = key;
    }
    __syncthreads();                               // B4 (rescan rk visible)
  }

  // ---- canonical relabel: assign[t] == min original index of t's cluster
  int f0 = (assign[rA] == rA) ? 1 : 0;
  int f1 = (assign[rB] == rB) ? 1 : 0;
  int c = f0 + f1;
  int incl = c;
#pragma unroll
  for (int off = 1; off < 64; off <<= 1) {
    int o = __shfl_up(incl, (unsigned)off, 64);
    if (lane >= off) incl += o;
  }
  if (lane == 63) wsum[w] = incl;
  __syncthreads();
  int base = incl - c;
  for (int q = 0; q < w; ++q) base += wsum[q];
  if (f0) rankArr[rA] = base;
  if (f1) rankArr[rB] = base + f0;
  __syncthreads();
  outp[(size_t)b * TT + rA] = rankArr[assign[rA]];
  outp[(size_t)b * TT + rB] = rankArr[assign[rB]];
}

extern "C" void kernel_launch(void* const* d_in, const int* in_sizes, int n_in,
                              void* d_out, int out_size, void* d_ws, size_t ws_size,
                              hipStream_t stream) {
  const float* x = (const float*)d_in[0];
  const int* ncp = (const int*)d_in[1];
  int B = in_sizes[0] / (TT * CC);
  float* dall = (float*)d_ws;                                   // B * 512*512 f32 (64 MiB)
  unsigned long long* rkall =
      (unsigned long long*)((char*)d_ws + (size_t)B * TT * TT * sizeof(float));
  int* outp = (int*)d_out;

  dim3 g1(TT / 64, B);
  build_dist_kernel<<<g1, 256, 0, stream>>>(x, dall, rkall);
  agglom_kernel<<<B, 256, 0, stream>>>(ncp, dall, rkall, outp);
}